// Round 3
// baseline (486.283 us; speedup 1.0000x reference)
//
#include <hip/hip_runtime.h>

static constexpr int B_ = 512, N_ = 32, D_ = 256, K_ = 8;
static constexpr int E1 = 40, E2 = 6;          // ee MLP dims 256->40->6->1
static constexpr int N1 = 81, N2 = 25, N3 = 8; // en MLP dims 256->81->25->8
static constexpr int XP = 257;                 // xs LDS row pad (257 % 32 == 1 -> conflict-free)
static constexpr float LN2f = 0.69314718055994530942f;

// shifted softplus: log(0.5*exp(x)+0.5) = softplus(x) - ln2, numerically stable
__device__ __forceinline__ float sspf(float x) {
    float ax = fabsf(x);
    float e  = __expf(-ax);
    return fmaxf(x, 0.f) + __logf(1.f + e) - LN2f;
}

// ---------------- kernel P: repack nw1 [256][81] -> nw1p [256][8][12] ------
// chunk s holds nw1[k][10s .. 10s+10] (11 values) + zero pad, 16B-aligned.
__global__ void k_pack(const float* __restrict__ nw1, float* __restrict__ nw1p) {
    int idx = blockIdx.x * 256 + threadIdx.x;   // 2048 = 256 k * 8 s
    int k = idx >> 3, s = idx & 7;
    const float* src = nw1 + k * N1 + s * 10;
    float* dst = nw1p + k * 96 + s * 12;
    #pragma unroll
    for (int u = 0; u < 11; ++u) dst[u] = src[u];
    dst[11] = 0.f;
}

// ---------------- kernel B: electron-nucleus part --------------------------
// writes bf_nuc [B,N,3] fp32 and cutoff [B,N] fp32 to workspace
__global__ __launch_bounds__(256) void k_en(
    const float* __restrict__ rs, const float* __restrict__ xs,
    const float* __restrict__ coords,
    const float* __restrict__ nw1p, const float* __restrict__ nb1,
    const float* __restrict__ nw2, const float* __restrict__ nb2,
    const float* __restrict__ nw3, const float* __restrict__ nb3,
    float* __restrict__ bfn_ws, float* __restrict__ cut_ws)
{
    __shared__ alignas(16) float xs_s[N_ * XP];
    __shared__ float h1_s[N_ * 84];
    __shared__ float h2_s[N_ * 26];
    __shared__ float rs_s[N_ * 3];
    __shared__ float nw2_s[N1 * N2];
    __shared__ float nw3_s[N2 * N3];
    __shared__ float nb1_s[N1];
    __shared__ float nb2_s[N2];
    __shared__ float nb3_s[N3];
    __shared__ float co_s[K_ * 3];

    const int b = blockIdx.x, t = threadIdx.x;

    // stage xs[b] (32x256 fp32) into LDS with row pad XP
    {
        const float4* src = (const float4*)(xs + (size_t)b * N_ * D_);
        #pragma unroll
        for (int u = 0; u < 8; ++u) {
            int q = t + 256 * u;            // 2048 float4 total
            float4 v = src[q];
            int row = q >> 6, col = (q & 63) * 4;
            float* dst = &xs_s[row * XP + col];
            dst[0] = v.x; dst[1] = v.y; dst[2] = v.z; dst[3] = v.w;
        }
    }
    if (t < N_ * 3) rs_s[t] = rs[b * N_ * 3 + t];
    for (int i = t; i < N1 * N2; i += 256) nw2_s[i] = nw2[i];
    if (t < N2 * N3) nw3_s[t] = nw3[t];
    if (t < N1) nb1_s[t] = nb1[t];
    if (t < N2) nb2_s[t] = nb2[t];
    if (t < N3) nb3_s[t] = nb3[t];
    if (t < K_ * 3) co_s[t] = coords[t];
    __syncthreads();

    const int r = t >> 3, s = t & 7;

    // ---- layer 1: 256 -> 81, thread (r,s) computes n0..n0+10 via packed f4 loads
    {
        const int n0 = s * 10;
        float acc[11];
        #pragma unroll
        for (int u = 0; u < 11; ++u) acc[u] = 0.f;
        const int rb = r * XP;
        const float4* wbase = (const float4*)(nw1p + s * 12);
        for (int k = 0; k < D_; ++k) {
            float xv = xs_s[rb + k];
            const float4* w4 = wbase + k * 24;   // k*96 floats
            float4 w0 = w4[0], w1 = w4[1], w2 = w4[2];
            acc[0]  = fmaf(xv, w0.x, acc[0]);
            acc[1]  = fmaf(xv, w0.y, acc[1]);
            acc[2]  = fmaf(xv, w0.z, acc[2]);
            acc[3]  = fmaf(xv, w0.w, acc[3]);
            acc[4]  = fmaf(xv, w1.x, acc[4]);
            acc[5]  = fmaf(xv, w1.y, acc[5]);
            acc[6]  = fmaf(xv, w1.z, acc[6]);
            acc[7]  = fmaf(xv, w1.w, acc[7]);
            acc[8]  = fmaf(xv, w2.x, acc[8]);
            acc[9]  = fmaf(xv, w2.y, acc[9]);
            acc[10] = fmaf(xv, w2.z, acc[10]);
        }
        #pragma unroll
        for (int u = 0; u < 11; ++u) {
            int n = n0 + u;
            if (u < 10 || s == 7) h1_s[r * 84 + n] = sspf(acc[u] + nb1_s[n]);
        }
    }
    __syncthreads();

    // ---- layer 2: 81 -> 25, thread (r,s) computes n0=3s..+3 (4 wide, store 3 unless s==7)
    {
        const int n0 = 3 * s;
        float acc[4] = {0.f, 0.f, 0.f, 0.f};
        const int rb = r * 84;
        for (int kk = 0; kk < N1; ++kk) {
            float hv = h1_s[rb + kk];
            const float* wrow = nw2_s + kk * N2 + n0;
            #pragma unroll
            for (int u = 0; u < 4; ++u) acc[u] = fmaf(hv, wrow[u], acc[u]);
        }
        #pragma unroll
        for (int u = 0; u < 4; ++u) {
            int n = n0 + u;
            if (u < 3 || s == 7) h2_s[r * 26 + n] = sspf(acc[u] + nb2_s[n]);
        }
    }
    __syncthreads();

    // ---- layer 3 + bf_nuc + cutoff; lane s owns nucleus s
    {
        float w = nb3_s[s];
        const int rb = r * 26;
        #pragma unroll
        for (int kk = 0; kk < N2; ++kk)
            w = fmaf(h2_s[rb + kk], nw3_s[kk * N3 + s], w);

        float dx = rs_s[r * 3 + 0] - co_s[s * 3 + 0];
        float dy = rs_s[r * 3 + 1] - co_s[s * 3 + 1];
        float dz = rs_s[r * 3 + 2] - co_s[s * 3 + 2];
        float cx = w * dx, cy = w * dy, cz = w * dz;
        #pragma unroll
        for (int m = 1; m < 8; m <<= 1) {
            cx += __shfl_xor(cx, m);
            cy += __shfl_xor(cy, m);
            cz += __shfl_xor(cz, m);
        }
        float rr  = sqrtf(dx * dx + dy * dy + dz * dz);
        float xsc = 2.f * rr;                 // r / L with L = 0.5
        float cf  = (xsc < 0.5f) ? xsc * xsc * (6.f - 8.f * xsc + 3.f * xsc * xsc) : 1.f;
        #pragma unroll
        for (int m = 1; m < 8; m <<= 1) cf *= __shfl_xor(cf, m);

        if (s == 0) {
            int gi = b * N_ + r;
            bfn_ws[gi * 3 + 0] = cx;
            bfn_ws[gi * 3 + 1] = cy;
            bfn_ws[gi * 3 + 2] = cz;
            cut_ws[gi] = cf;
        }
    }
}

// tail of the ee MLP for one accumulator array; macro-inlined (no array-by-ref
// function call -> guarantees SROA keeps ACC in VGPRs, no scratch spill)
#define EE_TAIL(ACC, I)                                                        \
    {                                                                          \
        _Pragma("unroll")                                                      \
        for (int u = 0; u < E1; ++u) ACC[u] = sspf(ACC[u] + eb1_s[u]);         \
        float h20 = 0.f, h21 = 0.f, h22 = 0.f, h23 = 0.f, h24 = 0.f, h25 = 0.f;\
        _Pragma("unroll")                                                      \
        for (int kk = 0; kk < E1; ++kk) {                                      \
            const float4* w2r = (const float4*)&ew2_s[kk * 8];                 \
            float4 a2 = w2r[0], b2 = w2r[1];                                   \
            float hv = ACC[kk];                                                \
            h20 = fmaf(hv, a2.x, h20);                                         \
            h21 = fmaf(hv, a2.y, h21);                                         \
            h22 = fmaf(hv, a2.z, h22);                                         \
            h23 = fmaf(hv, a2.w, h23);                                         \
            h24 = fmaf(hv, b2.x, h24);                                         \
            h25 = fmaf(hv, b2.y, h25);                                         \
        }                                                                      \
        float w = eb3v;                                                        \
        w = fmaf(sspf(h20 + eb2_s[0]), w3v[0], w);                             \
        w = fmaf(sspf(h21 + eb2_s[1]), w3v[1], w);                             \
        w = fmaf(sspf(h22 + eb2_s[2]), w3v[2], w);                             \
        w = fmaf(sspf(h23 + eb2_s[3]), w3v[3], w);                             \
        w = fmaf(sspf(h24 + eb2_s[4]), w3v[4], w);                             \
        w = fmaf(sspf(h25 + eb2_s[5]), w3v[5], w);                             \
        float cx = w * (rs_s[(I) * 3 + 0] - rjx);                              \
        float cy = w * (rs_s[(I) * 3 + 1] - rjy);                              \
        float cz = w * (rs_s[(I) * 3 + 2] - rjz);                              \
        _Pragma("unroll")                                                      \
        for (int m = 1; m < 32; m <<= 1) {                                     \
            cx += __shfl_xor(cx, m);                                           \
            cy += __shfl_xor(cy, m);                                           \
            cz += __shfl_xor(cz, m);                                           \
        }                                                                      \
        if (j == 0) {                                                          \
            bfe_s[(I) * 3 + 0] = cx;                                           \
            bfe_s[(I) * 3 + 1] = cy;                                           \
            bfe_s[(I) * 3 + 2] = cz;                                           \
        }                                                                      \
    }

// ---------------- kernel A: electron-electron part + combine ---------------
__global__ __launch_bounds__(256, 1) void k_ee(
    const float* __restrict__ rs, const float* __restrict__ xs,
    const float* __restrict__ ew1, const float* __restrict__ eb1,
    const float* __restrict__ ew2, const float* __restrict__ eb2,
    const float* __restrict__ ew3, const float* __restrict__ eb3,
    const float* __restrict__ bfn_ws, const float* __restrict__ cut_ws,
    float* __restrict__ out)
{
    __shared__ alignas(16) float xs_s[N_ * XP];
    __shared__ alignas(16) float ew1_s[D_ * E1];   // [256][40] fp32, 40 KB
    __shared__ float eb1_s[E1];
    __shared__ alignas(16) float ew2_s[E1 * 8];    // [40][8] padded
    __shared__ float eb2_s[8];
    __shared__ float ew3_s[E2];
    __shared__ float eb3_sv[1];
    __shared__ float rs_s[N_ * 3];
    __shared__ float bfe_s[N_ * 3];

    const int b = blockIdx.x, t = threadIdx.x;

    // stage xs[b]
    {
        const float4* src = (const float4*)(xs + (size_t)b * N_ * D_);
        #pragma unroll
        for (int u = 0; u < 8; ++u) {
            int q = t + 256 * u;
            float4 v = src[q];
            int row = q >> 6, col = (q & 63) * 4;
            float* dst = &xs_s[row * XP + col];
            dst[0] = v.x; dst[1] = v.y; dst[2] = v.z; dst[3] = v.w;
        }
    }
    // stage ew1 fp32 (exactly 40*256 = 2560 float4)
    {
        const float4* src = (const float4*)ew1;
        float4* dst = (float4*)ew1_s;
        #pragma unroll
        for (int u = 0; u < 10; ++u) {
            int idx = t + 256 * u;
            dst[idx] = src[idx];
        }
    }
    if (t < E1) eb1_s[t] = eb1[t];
    if (t < E1 * E2) { int kk = t / 6, n = t - kk * 6; ew2_s[kk * 8 + n] = ew2[t]; }
    if (t < E1) { ew2_s[t * 8 + 6] = 0.f; ew2_s[t * 8 + 7] = 0.f; }  // zero pads
    if (t < E2) ew3_s[t] = ew3[t];
    if (t == 0) eb3_sv[0] = eb3[0];
    if (t < 8) eb2_s[t] = (t < E2) ? eb2[t] : 0.f;
    if (t < N_ * 3) rs_s[t] = rs[b * N_ * 3 + t];
    __syncthreads();

    const int j = t & 31, g = t >> 5;
    const int jb = j * XP;
    const float rjx = rs_s[j * 3 + 0], rjy = rs_s[j * 3 + 1], rjz = rs_s[j * 3 + 2];
    float w3v[E2];
    #pragma unroll
    for (int u = 0; u < E2; ++u) w3v[u] = ew3_s[u];
    const float eb3v = eb3_sv[0];

    #pragma unroll 1
    for (int pass = 0; pass < 2; ++pass) {
        const int i0 = g + 16 * pass, i1 = i0 + 8;
        const int i0b = i0 * XP, i1b = i1 * XP;
        float acc0[E1], acc1[E1];
        #pragma unroll
        for (int u = 0; u < E1; ++u) { acc0[u] = 0.f; acc1[u] = 0.f; }

        #pragma unroll 1
        for (int k = 0; k < D_; ++k) {
            float jv = xs_s[jb + k];
            float p0 = jv * xs_s[i0b + k];
            float p1 = jv * xs_s[i1b + k];
            const float4* row4 = (const float4*)&ew1_s[k * E1];
            #pragma unroll
            for (int q = 0; q < 10; ++q) {
                float4 wv = row4[q];
                acc0[4 * q + 0] = fmaf(p0, wv.x, acc0[4 * q + 0]);
                acc0[4 * q + 1] = fmaf(p0, wv.y, acc0[4 * q + 1]);
                acc0[4 * q + 2] = fmaf(p0, wv.z, acc0[4 * q + 2]);
                acc0[4 * q + 3] = fmaf(p0, wv.w, acc0[4 * q + 3]);
                acc1[4 * q + 0] = fmaf(p1, wv.x, acc1[4 * q + 0]);
                acc1[4 * q + 1] = fmaf(p1, wv.y, acc1[4 * q + 1]);
                acc1[4 * q + 2] = fmaf(p1, wv.z, acc1[4 * q + 2]);
                acc1[4 * q + 3] = fmaf(p1, wv.w, acc1[4 * q + 3]);
            }
        }
        EE_TAIL(acc0, i0)
        EE_TAIL(acc1, i1)
    }
    __syncthreads();

    // combine and write output (fp32)
    if (t < N_ * 3) {
        int r = t / 3, c = t - 3 * r;
        int gi = b * N_ + r;
        float val = rs_s[t] + 1e-4f * cut_ws[gi] * (bfe_s[t] + bfn_ws[gi * 3 + c]);
        out[(size_t)b * (N_ * 3) + t] = val;
    }
}

extern "C" void kernel_launch(void* const* d_in, const int* in_sizes, int n_in,
                              void* d_out, int out_size, void* d_ws, size_t ws_size,
                              hipStream_t stream)
{
    const float* rs     = (const float*)d_in[0];
    const float* xs     = (const float*)d_in[1];
    const float* coords = (const float*)d_in[2];
    const float* ew1    = (const float*)d_in[3];
    const float* eb1    = (const float*)d_in[4];
    const float* ew2    = (const float*)d_in[5];
    const float* eb2    = (const float*)d_in[6];
    const float* ew3    = (const float*)d_in[7];
    const float* eb3    = (const float*)d_in[8];
    const float* nw1    = (const float*)d_in[9];
    const float* nb1    = (const float*)d_in[10];
    const float* nw2    = (const float*)d_in[11];
    const float* nb2    = (const float*)d_in[12];
    const float* nw3    = (const float*)d_in[13];
    const float* nb3    = (const float*)d_in[14];

    float* ws   = (float*)d_ws;
    float* nw1p = ws;                      // 256*96 = 24576 floats
    float* bfn  = ws + 24576;              // 49152 floats
    float* cut  = ws + 24576 + 49152;      // 16384 floats

    k_pack<<<8, 256, 0, stream>>>(nw1, nw1p);
    k_en<<<B_, 256, 0, stream>>>(rs, xs, coords, nw1p, nb1, nw2, nb2, nw3, nb3, bfn, cut);
    k_ee<<<B_, 256, 0, stream>>>(rs, xs, ew1, eb1, ew2, eb2, ew3, eb3, bfn, cut,
                                 (float*)d_out);
}

// Round 4
// 185.315 us; speedup vs baseline: 2.6241x; 2.6241x over previous
//
#include <hip/hip_runtime.h>
#include <stdint.h>

static constexpr int B_ = 512, N_ = 32, D_ = 256, K_ = 8;
static constexpr int E1 = 40, E2 = 6;          // ee MLP dims 256->40->6->1
static constexpr int N1 = 81, N2 = 25, N3 = 8; // en MLP dims 256->81->25->8
static constexpr int XBP = 264;                // xs_bf row stride (bf16), 528 B = 16B-aligned
static constexpr int H1P = 72;                 // h1t row stride (bf16), 144 B = 16B-aligned
static constexpr float LN2f = 0.69314718055994530942f;

typedef float    f32x4 __attribute__((ext_vector_type(4)));
typedef short    s16x8 __attribute__((ext_vector_type(8)));
typedef uint32_t u32x4 __attribute__((ext_vector_type(4)));

union FragU { u32x4 d; s16x8 v; };

__device__ __forceinline__ float sspf(float x) {
    float ax = fabsf(x);
    float e  = __expf(-ax);
    return fmaxf(x, 0.f) + __logf(1.f + e) - LN2f;
}

__device__ __forceinline__ uint32_t bf_rtne(float x) {
    uint32_t u = __float_as_uint(x);
    return (u + 0x7FFFu + ((u >> 16) & 1u)) >> 16;
}
__device__ __forceinline__ uint32_t pk_rtne(float lo, float hi) {
    return bf_rtne(lo) | (bf_rtne(hi) << 16);
}
// truncation pack (hot path; bias ~0.2% is far under error budget)
__device__ __forceinline__ uint32_t pk_trunc(float lo, float hi) {
    return (__float_as_uint(hi) & 0xFFFF0000u) | (__float_as_uint(lo) >> 16);
}

__global__ __launch_bounds__(256) void k_fused(
    const float* __restrict__ rs, const float* __restrict__ xs,
    const float* __restrict__ coords,
    const float* __restrict__ ew1, const float* __restrict__ eb1,
    const float* __restrict__ ew2, const float* __restrict__ eb2,
    const float* __restrict__ ew3, const float* __restrict__ eb3,
    const float* __restrict__ nw1, const float* __restrict__ nb1,
    const float* __restrict__ nw2, const float* __restrict__ nb2,
    const float* __restrict__ nw3, const float* __restrict__ nb3,
    float* __restrict__ out)
{
    __shared__ uint16_t xs_bf[N_ * XBP];        // xs in bf16, [32][264]
    __shared__ uint16_t h1t[4][16 * H1P];       // per-wave ee layer1->2 tile [16][72]
    __shared__ float h1e[N_ * 84];              // en hidden 1
    __shared__ float h2e[N_ * 26];              // en hidden 2
    __shared__ float w_s[N_ * N_];              // ee pair weights [i][j]
    __shared__ float nw2_s[N1 * N2];
    __shared__ float nw3_s[N2 * N3];
    __shared__ float rs_s[N_ * 3];
    __shared__ float nb2_s[N2];
    __shared__ float nb3_s[N3];
    __shared__ float co_s[K_ * 3];
    __shared__ float bfn_s[N_ * 3];
    __shared__ float cut_s[N_];

    const int b = blockIdx.x, t = threadIdx.x;
    const int wv = t >> 6, l = t & 63, quad = l >> 4, c = l & 15;

    // ---- stage xs[b] fp32 -> bf16 LDS (RTNE) ----
    {
        const float4* src = (const float4*)(xs + (size_t)b * N_ * D_);
        #pragma unroll
        for (int u = 0; u < 8; ++u) {
            int q = t + 256 * u;              // 2048 float4
            float4 v = src[q];
            int row = q >> 6, col4 = q & 63;
            uint32_t* dst = (uint32_t*)&xs_bf[row * XBP + col4 * 4];
            dst[0] = pk_rtne(v.x, v.y);
            dst[1] = pk_rtne(v.z, v.w);
        }
    }
    if (t < N_ * 3) rs_s[t] = rs[b * N_ * 3 + t];
    for (int i2 = t; i2 < N1 * N2; i2 += 256) nw2_s[i2] = nw2[i2];
    if (t < N2 * N3) nw3_s[t] = nw3[t];
    if (t < N2) nb2_s[t] = nb2[t];
    if (t < N3) nb3_s[t] = nb3[t];
    if (t < K_ * 3) co_s[t] = coords[t];
    // zero h1t cols 48..63 (never written by epilogue; must be finite for A2 reads)
    {
        unsigned long long* z =
            (unsigned long long*)&h1t[wv][c * H1P + 48 + quad * 4];
        *z = 0ull;
    }
    __syncthreads();   // B1: xs_bf ready

    // ---- en layer 1 via MFMA: h1e = ssp(xs @ nw1 + nb1), M=32,K=256,N=81(pad 96)
    // products p=0..11: (Mt=p&1, Nt=p>>1); wave wv owns p=3wv..3wv+2
    {
        #pragma unroll 1
        for (int e = 0; e < 3; ++e) {
            int p  = 3 * wv + e;
            int Mt = p & 1, Nt = p >> 1;
            int n  = Nt * 16 + c;
            bool nok = (n < N1);
            float nb1v = nok ? nb1[n] : 0.f;
            f32x4 acc = {0.f, 0.f, 0.f, 0.f};
            for (int Kt = 0; Kt < 8; ++Kt) {
                FragU bfr;
                #pragma unroll
                for (int d2 = 0; d2 < 4; ++d2) {
                    int k0 = Kt * 32 + quad * 8 + 2 * d2;
                    float w0 = nok ? nw1[k0 * N1 + n] : 0.f;
                    float w1 = nok ? nw1[(k0 + 1) * N1 + n] : 0.f;
                    bfr.d[d2] = pk_rtne(w0, w1);
                }
                FragU afr;
                afr.v = *(const s16x8*)&xs_bf[(Mt * 16 + c) * XBP + Kt * 32 + quad * 8];
                acc = __builtin_amdgcn_mfma_f32_16x16x32_bf16(afr.v, bfr.v, acc, 0, 0, 0);
            }
            if (nok) {
                #pragma unroll
                for (int r2 = 0; r2 < 4; ++r2) {
                    int m = Mt * 16 + quad * 4 + r2;   // C row = quad*4+reg
                    h1e[m * 84 + n] = sspf(acc[r2] + nb1v);
                }
            }
        }
    }

    // ---- ee B-fragments into registers (held for the whole kernel) ----
    s16x8 b1f[3][8];   // W1 [256][40->48], 96 VGPRs
    {
        #pragma unroll
        for (int Nt = 0; Nt < 3; ++Nt) {
            int n = Nt * 16 + c;
            bool nok = (n < E1);
            #pragma unroll
            for (int Kt = 0; Kt < 8; ++Kt) {
                FragU f;
                #pragma unroll
                for (int d2 = 0; d2 < 4; ++d2) {
                    int k0 = Kt * 32 + quad * 8 + 2 * d2;
                    float w0 = nok ? ew1[k0 * E1 + n] : 0.f;
                    float w1 = nok ? ew1[(k0 + 1) * E1 + n] : 0.f;
                    f.d[d2] = pk_rtne(w0, w1);
                }
                b1f[Nt][Kt] = f.v;
            }
        }
    }
    s16x8 b2f[2];      // W2 [40->64][6->16]
    {
        #pragma unroll
        for (int Kt = 0; Kt < 2; ++Kt) {
            FragU f;
            #pragma unroll
            for (int d2 = 0; d2 < 4; ++d2) {
                int k0 = Kt * 32 + quad * 8 + 2 * d2;
                float w0 = (k0 < E1 && c < E2) ? ew2[k0 * E2 + c] : 0.f;
                float w1 = (k0 + 1 < E1 && c < E2) ? ew2[(k0 + 1) * E2 + c] : 0.f;
                f.d[d2] = pk_rtne(w0, w1);
            }
            b2f[Kt] = f.v;
        }
    }
    float eb1v[3];
    #pragma unroll
    for (int Nt = 0; Nt < 3; ++Nt) { int n = Nt * 16 + c; eb1v[Nt] = (n < E1) ? eb1[n] : 0.f; }
    const float eb2v = (c < E2) ? eb2[c] : 0.f;
    const float w3v  = (c < E2) ? ew3[c] : 0.f;
    const float eb3v = eb3[0];

    __syncthreads();   // B2: h1e complete

    // ---- en layer 2 (VALU): h2e = ssp(h1e @ nw2 + nb2) ----
    {
        const int r = t >> 3, s = t & 7;
        const int n0 = 3 * s;
        float acc2[4] = {0.f, 0.f, 0.f, 0.f};
        const int rb = r * 84;
        for (int kk = 0; kk < N1; ++kk) {
            float hv = h1e[rb + kk];
            const float* wrow = nw2_s + kk * N2 + n0;
            #pragma unroll
            for (int u = 0; u < 4; ++u) acc2[u] = fmaf(hv, wrow[u], acc2[u]);
        }
        #pragma unroll
        for (int u = 0; u < 4; ++u) {
            int n = n0 + u;
            if (u < 3 || s == 7) h2e[r * 26 + n] = sspf(acc2[u] + nb2_s[n]);
        }
    }
    __syncthreads();   // B3: h2e complete

    // ---- en layer 3 + bf_nuc + cutoff ----
    {
        const int r = t >> 3, s = t & 7;
        float w = nb3_s[s];
        const int rb = r * 26;
        #pragma unroll
        for (int kk = 0; kk < N2; ++kk)
            w = fmaf(h2e[rb + kk], nw3_s[kk * N3 + s], w);

        float dx = rs_s[r * 3 + 0] - co_s[s * 3 + 0];
        float dy = rs_s[r * 3 + 1] - co_s[s * 3 + 1];
        float dz = rs_s[r * 3 + 2] - co_s[s * 3 + 2];
        float cx = w * dx, cy = w * dy, cz = w * dz;
        #pragma unroll
        for (int m2 = 1; m2 < 8; m2 <<= 1) {
            cx += __shfl_xor(cx, m2);
            cy += __shfl_xor(cy, m2);
            cz += __shfl_xor(cz, m2);
        }
        float rr  = sqrtf(dx * dx + dy * dy + dz * dz);
        float xsc = 2.f * rr;                 // r / L, L = 0.5
        float cf  = (xsc < 0.5f) ? xsc * xsc * (6.f - 8.f * xsc + 3.f * xsc * xsc) : 1.f;
        #pragma unroll
        for (int m2 = 1; m2 < 8; m2 <<= 1) cf *= __shfl_xor(cf, m2);
        if (s == 0) {
            bfn_s[r * 3 + 0] = cx;
            bfn_s[r * 3 + 1] = cy;
            bfn_s[r * 3 + 2] = cz;
            cut_s[r] = cf;
        }
    }

    // ---- ee main: per wave 8 i-values; Mt=2i,2i+1 (j=0..15 / 16..31) ----
    uint16_t* myh1 = &h1t[wv][0];
    #pragma unroll 1
    for (int q8 = 0; q8 < 8; ++q8) {
        const int i = wv + 4 * q8;
        f32x4 acc[2][3];
        #pragma unroll
        for (int h = 0; h < 2; ++h)
            #pragma unroll
            for (int Nt = 0; Nt < 3; ++Nt) acc[h][Nt] = (f32x4){0.f, 0.f, 0.f, 0.f};

        #pragma unroll
        for (int Kt = 0; Kt < 8; ++Kt) {
            const int koff = Kt * 32 + quad * 8;
            s16x8 iv  = *(const s16x8*)&xs_bf[i * XBP + koff];          // uniform/quad
            s16x8 jv0 = *(const s16x8*)&xs_bf[c * XBP + koff];          // rows 0..15
            s16x8 jv1 = *(const s16x8*)&xs_bf[(16 + c) * XBP + koff];   // rows 16..31
            const uint32_t* I  = (const uint32_t*)&iv;
            const uint32_t* J0 = (const uint32_t*)&jv0;
            const uint32_t* J1 = (const uint32_t*)&jv1;
            FragU A0, A1;
            #pragma unroll
            for (int d2 = 0; d2 < 4; ++d2) {
                float ilo = __uint_as_float(I[d2] << 16);
                float ihi = __uint_as_float(I[d2] & 0xFFFF0000u);
                float a0l = ilo * __uint_as_float(J0[d2] << 16);
                float a0h = ihi * __uint_as_float(J0[d2] & 0xFFFF0000u);
                float a1l = ilo * __uint_as_float(J1[d2] << 16);
                float a1h = ihi * __uint_as_float(J1[d2] & 0xFFFF0000u);
                A0.d[d2] = pk_trunc(a0l, a0h);
                A1.d[d2] = pk_trunc(a1l, a1h);
            }
            #pragma unroll
            for (int Nt = 0; Nt < 3; ++Nt) {
                acc[0][Nt] = __builtin_amdgcn_mfma_f32_16x16x32_bf16(A0.v, b1f[Nt][Kt], acc[0][Nt], 0, 0, 0);
                acc[1][Nt] = __builtin_amdgcn_mfma_f32_16x16x32_bf16(A1.v, b1f[Nt][Kt], acc[1][Nt], 0, 0, 0);
            }
        }

        // epilogue: h1 -> (LDS transform) -> layer2 MFMA -> layer3 -> w_s
        #pragma unroll
        for (int h = 0; h < 2; ++h) {
            #pragma unroll
            for (int Nt = 0; Nt < 3; ++Nt) {
                #pragma unroll
                for (int r2 = 0; r2 < 4; ++r2) {
                    float hv = sspf(acc[h][Nt][r2] + eb1v[Nt]);
                    myh1[(quad * 4 + r2) * H1P + Nt * 16 + c] = (uint16_t)bf_rtne(hv);
                }
            }
            f32x4 acc2 = {0.f, 0.f, 0.f, 0.f};
            #pragma unroll
            for (int Kt2 = 0; Kt2 < 2; ++Kt2) {
                s16x8 a2 = *(const s16x8*)&myh1[c * H1P + Kt2 * 32 + quad * 8];
                acc2 = __builtin_amdgcn_mfma_f32_16x16x32_bf16(a2, b2f[Kt2], acc2, 0, 0, 0);
            }
            float wp[4];
            #pragma unroll
            for (int r2 = 0; r2 < 4; ++r2) wp[r2] = sspf(acc2[r2] + eb2v) * w3v;
            #pragma unroll
            for (int m2 = 1; m2 < 16; m2 <<= 1) {
                #pragma unroll
                for (int r2 = 0; r2 < 4; ++r2) wp[r2] += __shfl_xor(wp[r2], m2);
            }
            if (c == 0) {
                int Mt = 2 * i + h;
                float4* dst = (float4*)&w_s[Mt * 16 + quad * 4];
                *dst = make_float4(wp[0] + eb3v, wp[1] + eb3v, wp[2] + eb3v, wp[3] + eb3v);
            }
        }
    }
    __syncthreads();   // B4: w_s, bfn_s, cut_s ready

    // ---- final: bf_elec contraction + combine + store ----
    {
        const int i = t >> 3, si = t & 7;
        const float4 wq = *(const float4*)&w_s[i * 32 + si * 4];
        const float rix = rs_s[i * 3 + 0], riy = rs_s[i * 3 + 1], riz = rs_s[i * 3 + 2];
        float cx = 0.f, cy = 0.f, cz = 0.f;
        const float wa[4] = {wq.x, wq.y, wq.z, wq.w};
        #pragma unroll
        for (int u = 0; u < 4; ++u) {
            int j = si * 4 + u;
            cx = fmaf(wa[u], rix - rs_s[j * 3 + 0], cx);
            cy = fmaf(wa[u], riy - rs_s[j * 3 + 1], cy);
            cz = fmaf(wa[u], riz - rs_s[j * 3 + 2], cz);
        }
        #pragma unroll
        for (int m2 = 1; m2 < 8; m2 <<= 1) {
            cx += __shfl_xor(cx, m2);
            cy += __shfl_xor(cy, m2);
            cz += __shfl_xor(cz, m2);
        }
        if (si < 3) {
            float bfe = (si == 0) ? cx : ((si == 1) ? cy : cz);
            int idx = i * 3 + si;
            out[(size_t)b * (N_ * 3) + idx] =
                rs_s[idx] + 1e-4f * cut_s[i] * (bfe + bfn_s[idx]);
        }
    }
}

extern "C" void kernel_launch(void* const* d_in, const int* in_sizes, int n_in,
                              void* d_out, int out_size, void* d_ws, size_t ws_size,
                              hipStream_t stream)
{
    const float* rs     = (const float*)d_in[0];
    const float* xs     = (const float*)d_in[1];
    const float* coords = (const float*)d_in[2];
    const float* ew1    = (const float*)d_in[3];
    const float* eb1    = (const float*)d_in[4];
    const float* ew2    = (const float*)d_in[5];
    const float* eb2    = (const float*)d_in[6];
    const float* ew3    = (const float*)d_in[7];
    const float* eb3    = (const float*)d_in[8];
    const float* nw1    = (const float*)d_in[9];
    const float* nb1    = (const float*)d_in[10];
    const float* nw2    = (const float*)d_in[11];
    const float* nb2    = (const float*)d_in[12];
    const float* nw3    = (const float*)d_in[13];
    const float* nb3    = (const float*)d_in[14];

    k_fused<<<B_, 256, 0, stream>>>(rs, xs, coords, ew1, eb1, ew2, eb2, ew3, eb3,
                                    nw1, nb1, nw2, nb2, nw3, nb3, (float*)d_out);
}

// Round 5
// 173.184 us; speedup vs baseline: 2.8079x; 1.0700x over previous
//
#include <hip/hip_runtime.h>
#include <stdint.h>

static constexpr int B_ = 512, N_ = 32, D_ = 256, K_ = 8;
static constexpr int E1 = 40, E2 = 6;          // ee MLP dims 256->40->6->1
static constexpr int N1 = 81, N2 = 25, N3 = 8; // en MLP dims 256->81->25->8
static constexpr int XBP = 264;                // xs_bf row stride (bf16), 528 B = 16B-aligned
static constexpr int H1P = 72;                 // h1t row stride (bf16), 144 B = 16B-aligned
static constexpr int HEP = 88;                 // h1e row stride (bf16)
static constexpr float LN2f = 0.69314718055994530942f;

typedef float    f32x4 __attribute__((ext_vector_type(4)));
typedef short    s16x8 __attribute__((ext_vector_type(8)));
typedef uint32_t u32x4 __attribute__((ext_vector_type(4)));

union FragU { u32x4 d; s16x8 v; };

__device__ __forceinline__ float sspf(float x) {
    float ax = fabsf(x);
    float e  = __expf(-ax);
    return fmaxf(x, 0.f) + __logf(1.f + e) - LN2f;
}

__device__ __forceinline__ uint32_t bf_rtne(float x) {
    uint32_t u = __float_as_uint(x);
    return (u + 0x7FFFu + ((u >> 16) & 1u)) >> 16;
}
__device__ __forceinline__ uint32_t pk_rtne(float lo, float hi) {
    return bf_rtne(lo) | (bf_rtne(hi) << 16);
}
// truncation pack (hot path; bias ~0.2% is far under error budget)
__device__ __forceinline__ uint32_t pk_trunc(float lo, float hi) {
    return (__float_as_uint(hi) & 0xFFFF0000u) | (__float_as_uint(lo) >> 16);
}

// ---- prep: build bf16 MFMA B-fragment images in ws (run once per launch) ----
// ew1f: [3 Nt][8 Kt][64 lanes][4 dw]  (24 KB)
// nw1f: [6 Nt][8 Kt][64 lanes][4 dw]  (48 KB)
// w2f : [2 Kt][64 lanes][4 dw]        (2 KB)
__global__ __launch_bounds__(256) void k_prep(
    const float* __restrict__ ew1, const float* __restrict__ ew2,
    const float* __restrict__ nw1,
    u32x4* __restrict__ ew1f, u32x4* __restrict__ nw1f, u32x4* __restrict__ w2f)
{
    const int wv = threadIdx.x >> 6, l = threadIdx.x & 63;
    const int quad = l >> 4, c = l & 15;
    const int w = blockIdx.x * 4 + wv;
    u32x4 d;
    if (w < 24) {                       // ew1 frag, Nt=w>>3, Kt=w&7
        int Nt = w >> 3, Kt = w & 7;
        int n = Nt * 16 + c;
        bool ok = (n < E1);
        #pragma unroll
        for (int d2 = 0; d2 < 4; ++d2) {
            int k0 = Kt * 32 + quad * 8 + 2 * d2;
            float w0 = ok ? ew1[k0 * E1 + n] : 0.f;
            float w1 = ok ? ew1[(k0 + 1) * E1 + n] : 0.f;
            d[d2] = pk_rtne(w0, w1);
        }
        ew1f[w * 64 + l] = d;
    } else if (w < 72) {                // nw1 frag
        int idx = w - 24;
        int Nt = idx >> 3, Kt = idx & 7;
        int n = Nt * 16 + c;
        bool ok = (n < N1);
        #pragma unroll
        for (int d2 = 0; d2 < 4; ++d2) {
            int k0 = Kt * 32 + quad * 8 + 2 * d2;
            float w0 = ok ? nw1[k0 * N1 + n] : 0.f;
            float w1 = ok ? nw1[(k0 + 1) * N1 + n] : 0.f;
            d[d2] = pk_rtne(w0, w1);
        }
        nw1f[idx * 64 + l] = d;
    } else if (w < 74) {                // ew2 frag, Kt=w-72
        int Kt = w - 72;
        #pragma unroll
        for (int d2 = 0; d2 < 4; ++d2) {
            int k0 = Kt * 32 + quad * 8 + 2 * d2;
            float w0 = (k0 < E1 && c < E2) ? ew2[k0 * E2 + c] : 0.f;
            float w1 = (k0 + 1 < E1 && c < E2) ? ew2[(k0 + 1) * E2 + c] : 0.f;
            d[d2] = pk_rtne(w0, w1);
        }
        w2f[Kt * 64 + l] = d;
    }
}

__global__ __launch_bounds__(256) void k_fused(
    const float* __restrict__ rs, const float* __restrict__ xs,
    const float* __restrict__ coords,
    const u32x4* __restrict__ ew1f, const float* __restrict__ eb1,
    const u32x4* __restrict__ w2f, const float* __restrict__ eb2,
    const float* __restrict__ ew3, const float* __restrict__ eb3,
    const u32x4* __restrict__ nw1f, const float* __restrict__ nb1,
    const float* __restrict__ nw2, const float* __restrict__ nb2,
    const float* __restrict__ nw3, const float* __restrict__ nb3,
    float* __restrict__ out)
{
    __shared__ uint16_t xs_bf[N_ * XBP];        // xs in bf16, [32][264]
    __shared__ uint16_t h1t[4][16 * H1P];       // per-wave ee layer1->2 tile [16][72]
    __shared__ uint16_t h1e[N_ * HEP];          // en hidden 1 (bf16)
    __shared__ float h2e[N_ * 26];              // en hidden 2
    __shared__ float w_s[N_ * N_];              // ee pair weights [i][j]
    __shared__ float nw2_s[N1 * N2];
    __shared__ float nw3_s[N2 * N3];
    __shared__ float rs_s[N_ * 3];
    __shared__ float nb2_s[N2];
    __shared__ float nb3_s[N3];
    __shared__ float co_s[K_ * 3];
    __shared__ float bfn_s[N_ * 3];
    __shared__ float cut_s[N_];

    const int b = blockIdx.x, t = threadIdx.x;
    const int wv = t >> 6, l = t & 63, quad = l >> 4, c = l & 15;

    // ---- ee/en weight fragments: coalesced loads (no LDS dependency) ----
    s16x8 b1f[3][8];   // W1 [256][40->48], 96 VGPRs
    #pragma unroll
    for (int Nt = 0; Nt < 3; ++Nt)
        #pragma unroll
        for (int Kt = 0; Kt < 8; ++Kt) {
            FragU f; f.d = ew1f[(Nt * 8 + Kt) * 64 + l];
            b1f[Nt][Kt] = f.v;
        }
    s16x8 b2f[2];      // W2 [40->64][6->16]
    #pragma unroll
    for (int Kt = 0; Kt < 2; ++Kt) {
        FragU f; f.d = w2f[Kt * 64 + l];
        b2f[Kt] = f.v;
    }
    float eb1v[3];
    #pragma unroll
    for (int Nt = 0; Nt < 3; ++Nt) { int n = Nt * 16 + c; eb1v[Nt] = (n < E1) ? eb1[n] : 0.f; }
    const float eb2v = (c < E2) ? eb2[c] : 0.f;
    const float w3v  = (c < E2) ? ew3[c] : 0.f;
    const float eb3v = eb3[0];

    // ---- stage xs[b] fp32 -> bf16 LDS (RTNE) ----
    {
        const float4* src = (const float4*)(xs + (size_t)b * N_ * D_);
        #pragma unroll
        for (int u = 0; u < 8; ++u) {
            int q = t + 256 * u;              // 2048 float4
            float4 v = src[q];
            int row = q >> 6, col4 = q & 63;
            uint32_t* dst = (uint32_t*)&xs_bf[row * XBP + col4 * 4];
            dst[0] = pk_rtne(v.x, v.y);
            dst[1] = pk_rtne(v.z, v.w);
        }
    }
    if (t < N_ * 3) rs_s[t] = rs[b * N_ * 3 + t];
    for (int i2 = t; i2 < N1 * N2; i2 += 256) nw2_s[i2] = nw2[i2];
    if (t < N2 * N3) nw3_s[t] = nw3[t];
    if (t < N2) nb2_s[t] = nb2[t];
    if (t < N3) nb3_s[t] = nb3[t];
    if (t < K_ * 3) co_s[t] = coords[t];
    // zero h1t cols 48..63 (never written by epilogue; must be finite for A2 reads)
    {
        unsigned long long* z =
            (unsigned long long*)&h1t[wv][c * H1P + 48 + quad * 4];
        *z = 0ull;
    }
    __syncthreads();   // B1: xs_bf ready

    // ---- en layer 1 via MFMA: h1e = ssp(xs @ nw1 + nb1), M=32,K=256,N=81(pad 96)
    // products p=0..11: (Mt=p&1, Nt=p>>1); wave wv owns p=3wv..3wv+2
    {
        #pragma unroll 1
        for (int e = 0; e < 3; ++e) {
            int p  = 3 * wv + e;
            int Mt = p & 1, Nt = p >> 1;
            int n  = Nt * 16 + c;
            bool nok = (n < N1);
            float nb1v = nok ? nb1[n] : 0.f;
            f32x4 acc = {0.f, 0.f, 0.f, 0.f};
            for (int Kt = 0; Kt < 8; ++Kt) {
                FragU bfr; bfr.d = nw1f[(Nt * 8 + Kt) * 64 + l];
                FragU afr;
                afr.v = *(const s16x8*)&xs_bf[(Mt * 16 + c) * XBP + Kt * 32 + quad * 8];
                acc = __builtin_amdgcn_mfma_f32_16x16x32_bf16(afr.v, bfr.v, acc, 0, 0, 0);
            }
            if (nok) {
                #pragma unroll
                for (int r2 = 0; r2 < 4; ++r2) {
                    int m = Mt * 16 + quad * 4 + r2;   // C row = quad*4+reg
                    h1e[m * HEP + n] = (uint16_t)bf_rtne(sspf(acc[r2] + nb1v));
                }
            }
        }
    }
    __syncthreads();   // B2: h1e complete

    // ---- en layer 2 (VALU): h2e = ssp(h1e @ nw2 + nb2) ----
    {
        const int r = t >> 3, s = t & 7;
        const int n0 = 3 * s;
        float acc2[4] = {0.f, 0.f, 0.f, 0.f};
        const int rb = r * HEP;
        for (int kk = 0; kk < N1; ++kk) {
            float hv = __uint_as_float(((uint32_t)h1e[rb + kk]) << 16);
            const float* wrow = nw2_s + kk * N2 + n0;
            #pragma unroll
            for (int u = 0; u < 4; ++u) acc2[u] = fmaf(hv, wrow[u], acc2[u]);
        }
        #pragma unroll
        for (int u = 0; u < 4; ++u) {
            int n = n0 + u;
            if (u < 3 || s == 7) h2e[r * 26 + n] = sspf(acc2[u] + nb2_s[n]);
        }
    }
    __syncthreads();   // B3: h2e complete

    // ---- en layer 3 + bf_nuc + cutoff ----
    {
        const int r = t >> 3, s = t & 7;
        float w = nb3_s[s];
        const int rb = r * 26;
        #pragma unroll
        for (int kk = 0; kk < N2; ++kk)
            w = fmaf(h2e[rb + kk], nw3_s[kk * N3 + s], w);

        float dx = rs_s[r * 3 + 0] - co_s[s * 3 + 0];
        float dy = rs_s[r * 3 + 1] - co_s[s * 3 + 1];
        float dz = rs_s[r * 3 + 2] - co_s[s * 3 + 2];
        float cx = w * dx, cy = w * dy, cz = w * dz;
        #pragma unroll
        for (int m2 = 1; m2 < 8; m2 <<= 1) {
            cx += __shfl_xor(cx, m2);
            cy += __shfl_xor(cy, m2);
            cz += __shfl_xor(cz, m2);
        }
        float rr  = sqrtf(dx * dx + dy * dy + dz * dz);
        float xsc = 2.f * rr;                 // r / L, L = 0.5
        float cf  = (xsc < 0.5f) ? xsc * xsc * (6.f - 8.f * xsc + 3.f * xsc * xsc) : 1.f;
        #pragma unroll
        for (int m2 = 1; m2 < 8; m2 <<= 1) cf *= __shfl_xor(cf, m2);
        if (s == 0) {
            bfn_s[r * 3 + 0] = cx;
            bfn_s[r * 3 + 1] = cy;
            bfn_s[r * 3 + 2] = cz;
            cut_s[r] = cf;
        }
    }

    // ---- ee main: per wave 8 i-values; h=0/1 -> j=0..15 / 16..31 ----
    uint16_t* myh1 = &h1t[wv][0];
    #pragma unroll 1
    for (int q8 = 0; q8 < 8; ++q8) {
        const int i = wv + 4 * q8;
        f32x4 acc[2][3];
        #pragma unroll
        for (int h = 0; h < 2; ++h)
            #pragma unroll
            for (int Nt = 0; Nt < 3; ++Nt) acc[h][Nt] = (f32x4){0.f, 0.f, 0.f, 0.f};

        #pragma unroll
        for (int Kt = 0; Kt < 8; ++Kt) {
            const int koff = Kt * 32 + quad * 8;
            s16x8 iv  = *(const s16x8*)&xs_bf[i * XBP + koff];          // uniform/quad
            s16x8 jv0 = *(const s16x8*)&xs_bf[c * XBP + koff];          // rows 0..15
            s16x8 jv1 = *(const s16x8*)&xs_bf[(16 + c) * XBP + koff];   // rows 16..31
            const uint32_t* I  = (const uint32_t*)&iv;
            const uint32_t* J0 = (const uint32_t*)&jv0;
            const uint32_t* J1 = (const uint32_t*)&jv1;
            FragU A0, A1;
            #pragma unroll
            for (int d2 = 0; d2 < 4; ++d2) {
                float ilo = __uint_as_float(I[d2] << 16);
                float ihi = __uint_as_float(I[d2] & 0xFFFF0000u);
                float a0l = ilo * __uint_as_float(J0[d2] << 16);
                float a0h = ihi * __uint_as_float(J0[d2] & 0xFFFF0000u);
                float a1l = ilo * __uint_as_float(J1[d2] << 16);
                float a1h = ihi * __uint_as_float(J1[d2] & 0xFFFF0000u);
                A0.d[d2] = pk_trunc(a0l, a0h);
                A1.d[d2] = pk_trunc(a1l, a1h);
            }
            #pragma unroll
            for (int Nt = 0; Nt < 3; ++Nt) {
                acc[0][Nt] = __builtin_amdgcn_mfma_f32_16x16x32_bf16(A0.v, b1f[Nt][Kt], acc[0][Nt], 0, 0, 0);
                acc[1][Nt] = __builtin_amdgcn_mfma_f32_16x16x32_bf16(A1.v, b1f[Nt][Kt], acc[1][Nt], 0, 0, 0);
            }
        }

        // epilogue: h1 -> (LDS transform) -> layer2 MFMA -> layer3 -> w_s
        #pragma unroll
        for (int h = 0; h < 2; ++h) {
            #pragma unroll
            for (int Nt = 0; Nt < 3; ++Nt) {
                #pragma unroll
                for (int r2 = 0; r2 < 4; ++r2) {
                    float hv = sspf(acc[h][Nt][r2] + eb1v[Nt]);
                    myh1[(quad * 4 + r2) * H1P + Nt * 16 + c] = (uint16_t)bf_rtne(hv);
                }
            }
            f32x4 acc2 = {0.f, 0.f, 0.f, 0.f};
            #pragma unroll
            for (int Kt2 = 0; Kt2 < 2; ++Kt2) {
                s16x8 a2 = *(const s16x8*)&myh1[c * H1P + Kt2 * 32 + quad * 8];
                acc2 = __builtin_amdgcn_mfma_f32_16x16x32_bf16(a2, b2f[Kt2], acc2, 0, 0, 0);
            }
            float wp[4];
            #pragma unroll
            for (int r2 = 0; r2 < 4; ++r2) wp[r2] = sspf(acc2[r2] + eb2v) * w3v;
            #pragma unroll
            for (int m2 = 1; m2 < 16; m2 <<= 1) {
                #pragma unroll
                for (int r2 = 0; r2 < 4; ++r2) wp[r2] += __shfl_xor(wp[r2], m2);
            }
            if (c == 0) {
                int Mt = 2 * i + h;
                float4* dst = (float4*)&w_s[Mt * 16 + quad * 4];
                *dst = make_float4(wp[0] + eb3v, wp[1] + eb3v, wp[2] + eb3v, wp[3] + eb3v);
            }
        }
    }
    __syncthreads();   // B4: w_s, bfn_s, cut_s ready

    // ---- final: bf_elec contraction + combine + store ----
    {
        const int i = t >> 3, si = t & 7;
        const float4 wq = *(const float4*)&w_s[i * 32 + si * 4];
        const float rix = rs_s[i * 3 + 0], riy = rs_s[i * 3 + 1], riz = rs_s[i * 3 + 2];
        float cx = 0.f, cy = 0.f, cz = 0.f;
        const float wa[4] = {wq.x, wq.y, wq.z, wq.w};
        #pragma unroll
        for (int u = 0; u < 4; ++u) {
            int j = si * 4 + u;
            cx = fmaf(wa[u], rix - rs_s[j * 3 + 0], cx);
            cy = fmaf(wa[u], riy - rs_s[j * 3 + 1], cy);
            cz = fmaf(wa[u], riz - rs_s[j * 3 + 2], cz);
        }
        #pragma unroll
        for (int m2 = 1; m2 < 8; m2 <<= 1) {
            cx += __shfl_xor(cx, m2);
            cy += __shfl_xor(cy, m2);
            cz += __shfl_xor(cz, m2);
        }
        if (si < 3) {
            float bfe = (si == 0) ? cx : ((si == 1) ? cy : cz);
            int idx = i * 3 + si;
            out[(size_t)b * (N_ * 3) + idx] =
                rs_s[idx] + 1e-4f * cut_s[i] * (bfe + bfn_s[idx]);
        }
    }
}

extern "C" void kernel_launch(void* const* d_in, const int* in_sizes, int n_in,
                              void* d_out, int out_size, void* d_ws, size_t ws_size,
                              hipStream_t stream)
{
    const float* rs     = (const float*)d_in[0];
    const float* xs     = (const float*)d_in[1];
    const float* coords = (const float*)d_in[2];
    const float* ew1    = (const float*)d_in[3];
    const float* eb1    = (const float*)d_in[4];
    const float* ew2    = (const float*)d_in[5];
    const float* eb2    = (const float*)d_in[6];
    const float* ew3    = (const float*)d_in[7];
    const float* eb3    = (const float*)d_in[8];
    const float* nw1    = (const float*)d_in[9];
    const float* nb1    = (const float*)d_in[10];
    const float* nw2    = (const float*)d_in[11];
    const float* nb2    = (const float*)d_in[12];
    const float* nw3    = (const float*)d_in[13];
    const float* nb3    = (const float*)d_in[14];

    u32x4* ws   = (u32x4*)d_ws;
    u32x4* ew1f = ws;                  // 24*64 u32x4 = 24 KB
    u32x4* nw1f = ws + 24 * 64;        // 48*64 u32x4 = 48 KB
    u32x4* w2f  = ws + 72 * 64;        // 2*64 u32x4  = 2 KB

    k_prep<<<19, 256, 0, stream>>>(ew1, ew2, nw1, ew1f, nw1f, w2f);
    k_fused<<<B_, 256, 0, stream>>>(rs, xs, coords, ew1f, eb1, w2f, eb2, ew3, eb3,
                                    nw1f, nb1, nw2, nb2, nw3, nb3, (float*)d_out);
}